// Round 4
// baseline (1746.191 us; speedup 1.0000x reference)
//
#include <hip/hip_runtime.h>

// HGNN aggregation: out = x + segment_sum(x[src_idx], dst_idx)
// x: [100000, 128] f32; src_idx/dst_idx: [2,000,000] int32.
//
// Round 4: bucket partition + LDS accumulation (no per-node CSR, no f32
// global atomics).
//   1. histogram dst>>7 into 782 buckets (LDS-privatized)
//   2. single-block scan -> bucketBase, cursor
//   3. partition: per-block LDS histogram + one global reservation per
//      (block,bucket), edges packed src|(dstLocal<<17) into 4B each
//   4. aggregate: one block per bucket, 64KB LDS accum[128][128],
//      conflict-free ds_add_f32, out = x + accum

constexpr int DIM = 128;
constexpr int BSHIFT = 7;            // 128 nodes per bucket
constexpr int GNODES = 1 << BSHIFT;  // 128
constexpr int MAXB = 1024;           // max buckets supported (N <= 131072)
constexpr int CE = 8192;             // edges per partition block

__global__ void hgnn_hist(const int* __restrict__ dst, int* __restrict__ gcount,
                          int nedges, int nbk) {
    __shared__ int h[MAXB];
    for (int i = threadIdx.x; i < nbk; i += blockDim.x) h[i] = 0;
    __syncthreads();
    int i = blockIdx.x * blockDim.x + threadIdx.x;
    int stride = gridDim.x * blockDim.x;
    for (; i < nedges; i += stride) atomicAdd(&h[dst[i] >> BSHIFT], 1);
    __syncthreads();
    for (int i2 = threadIdx.x; i2 < nbk; i2 += blockDim.x)
        if (h[i2]) atomicAdd(&gcount[i2], h[i2]);
}

// single block of 1024 threads; nbk <= 1024
__global__ void hgnn_scan(const int* __restrict__ gcount, int* __restrict__ base,
                          int* __restrict__ cursor, int nbk) {
    __shared__ int s[1024];
    int t = threadIdx.x;
    int v = (t < nbk) ? gcount[t] : 0;
    s[t] = v;
    __syncthreads();
    for (int off = 1; off < 1024; off <<= 1) {
        int val = (t >= off) ? s[t - off] : 0;
        __syncthreads();
        s[t] += val;
        __syncthreads();
    }
    if (t < nbk) {
        int excl = s[t] - v;
        base[t] = excl;
        cursor[t] = excl;
    }
    if (t == nbk - 1) base[nbk] = s[t];
}

__global__ void hgnn_partition(const int* __restrict__ src,
                               const int* __restrict__ dst,
                               int* __restrict__ cursor,
                               int* __restrict__ part,
                               int nedges, int nbk) {
    __shared__ int h[MAXB];
    __shared__ int lb[MAXB];
    int c0 = blockIdx.x * CE;
    int c1 = min(c0 + CE, nedges);
    for (int i = threadIdx.x; i < nbk; i += blockDim.x) h[i] = 0;
    __syncthreads();
    for (int i = c0 + threadIdx.x; i < c1; i += blockDim.x)
        atomicAdd(&h[dst[i] >> BSHIFT], 1);
    __syncthreads();
    for (int i = threadIdx.x; i < nbk; i += blockDim.x)
        lb[i] = h[i] ? atomicAdd(&cursor[i], h[i]) : 0;
    __syncthreads();
    for (int i = c0 + threadIdx.x; i < c1; i += blockDim.x) {
        int d = dst[i];
        int bk = d >> BSHIFT;
        int pos = atomicAdd(&lb[bk], 1);
        part[pos] = src[i] | ((d & (GNODES - 1)) << 17);
    }
}

// one block (4 waves, 256 thr) per bucket; 64KB LDS accumulator
__global__ void hgnn_aggregate(const float* __restrict__ x,
                               const int* __restrict__ part,
                               const int* __restrict__ base,
                               float* __restrict__ out, int nnodes) {
    __shared__ float accum[GNODES * DIM];   // 64 KB
    const int b = blockIdx.x;
    const int tid = threadIdx.x;
    const int wv = tid >> 6;      // 0..3
    const int lane = tid & 63;

    // zero accumulator
    {
        float4* a4 = (float4*)accum;
        for (int i = tid; i < GNODES * DIM / 4; i += 256)
            a4[i] = make_float4(0.f, 0.f, 0.f, 0.f);
    }
    __syncthreads();

    const int pbeg = base[b];
    const int cnt = base[b + 1] - pbeg;
    const int* pp = part + pbeg;

    int e = wv;
    // 4-deep unroll across this wave's strided edges (stride 4 waves)
    for (; e + 12 < cnt; e += 16) {
        int p0 = pp[e];
        int p1 = pp[e + 4];
        int p2 = pp[e + 8];
        int p3 = pp[e + 12];
        int s0 = p0 & 0x1FFFF, d0 = p0 >> 17;
        int s1 = p1 & 0x1FFFF, d1 = p1 >> 17;
        int s2 = p2 & 0x1FFFF, d2 = p2 >> 17;
        int s3 = p3 & 0x1FFFF, d3 = p3 >> 17;
        float a0 = x[s0 * DIM + lane], b0 = x[s0 * DIM + 64 + lane];
        float a1 = x[s1 * DIM + lane], b1 = x[s1 * DIM + 64 + lane];
        float a2 = x[s2 * DIM + lane], b2 = x[s2 * DIM + 64 + lane];
        float a3 = x[s3 * DIM + lane], b3 = x[s3 * DIM + 64 + lane];
        atomicAdd(&accum[d0 * DIM + lane], a0);
        atomicAdd(&accum[d0 * DIM + 64 + lane], b0);
        atomicAdd(&accum[d1 * DIM + lane], a1);
        atomicAdd(&accum[d1 * DIM + 64 + lane], b1);
        atomicAdd(&accum[d2 * DIM + lane], a2);
        atomicAdd(&accum[d2 * DIM + 64 + lane], b2);
        atomicAdd(&accum[d3 * DIM + lane], a3);
        atomicAdd(&accum[d3 * DIM + 64 + lane], b3);
    }
    for (; e < cnt; e += 4) {
        int p = pp[e];
        int s = p & 0x1FFFF, d = p >> 17;
        float a = x[s * DIM + lane], bb = x[s * DIM + 64 + lane];
        atomicAdd(&accum[d * DIM + lane], a);
        atomicAdd(&accum[d * DIM + 64 + lane], bb);
    }
    __syncthreads();

    // writeout: out[node] = x[node] + accum[row], 128 rows, float4 lanes
    const int nodeBase = b << BSHIFT;
    const float4* x4 = (const float4*)x;
    const float4* a4 = (const float4*)accum;
    float4* o4 = (float4*)out;
    const int c4 = tid & 31;            // 32 float4 per row
    const int r0 = tid >> 5;            // 8 rows at a time
    for (int r = r0; r < GNODES; r += 8) {
        int node = nodeBase + r;
        if (node < nnodes) {
            float4 xv = x4[node * (DIM / 4) + c4];
            float4 av = a4[r * (DIM / 4) + c4];
            o4[node * (DIM / 4) + c4] =
                make_float4(xv.x + av.x, xv.y + av.y, xv.z + av.z, xv.w + av.w);
        }
    }
}

extern "C" void kernel_launch(void* const* d_in, const int* in_sizes, int n_in,
                              void* d_out, int out_size, void* d_ws, size_t ws_size,
                              hipStream_t stream) {
    const float* x = (const float*)d_in[0];
    const int* src = (const int*)d_in[1];
    const int* dst = (const int*)d_in[2];
    float* out = (float*)d_out;

    const int E = in_sizes[1];                 // 2,000,000
    const int N = in_sizes[0] / DIM;           // 100,000
    const int NBK = (N + GNODES - 1) >> BSHIFT;  // 782

    // workspace layout (ints)
    int* ws = (int*)d_ws;
    int* gcount = ws;                 // [NBK]
    int* base   = gcount + MAXB;      // [NBK+1]
    int* cursor = base + MAXB + 1;    // [NBK]
    int* part   = cursor + MAXB;      // [E]

    hipMemsetAsync(gcount, 0, (size_t)NBK * sizeof(int), stream);

    hipLaunchKernelGGL(hgnn_hist, dim3(1024), dim3(256), 0, stream,
                       dst, gcount, E, NBK);
    hipLaunchKernelGGL(hgnn_scan, dim3(1), dim3(1024), 0, stream,
                       gcount, base, cursor, NBK);
    hipLaunchKernelGGL(hgnn_partition, dim3((E + CE - 1) / CE), dim3(256), 0, stream,
                       src, dst, cursor, part, E, NBK);
    hipLaunchKernelGGL(hgnn_aggregate, dim3(NBK), dim3(256), 0, stream,
                       x, part, base, out, N);
}

// Round 5
// 232.865 us; speedup vs baseline: 7.4987x; 7.4987x over previous
//
#include <hip/hip_runtime.h>

// HGNN aggregation: out = x + segment_sum(x[src_idx], dst_idx)
// x: [100000, 128] f32; src_idx/dst_idx: [2,000,000] int32.
//
// Round 5: 2-pass radix sort by dst + wave-per-node gather.
//   1. bucket hist (dst>>7, 782 buckets) + scan          (~15 us)
//   2. partition: packed src|(dstLocal<<17), clustered   (~35 us)
//   3. refine: per-bucket LDS sort by node -> in-place,
//      writes exact per-node offsets                     (~15 us)
//   4. aggregate: one wave per node, float2 lanes,
//      4-deep unroll, NO LDS -> high occupancy/TLP       (~160 us)

constexpr int DIM = 128;
constexpr int BSHIFT = 7;            // 128 nodes per bucket
constexpr int GNODES = 1 << BSHIFT;  // 128
constexpr int MAXB = 1024;           // max buckets (N <= 131072)
constexpr int CE = 8192;             // edges per partition block
constexpr int CAP = 8192;            // refine LDS staging capacity (32 KB)

__global__ void hgnn_hist(const int* __restrict__ dst, int* __restrict__ gcount,
                          int nedges, int nbk) {
    __shared__ int h[MAXB];
    for (int i = threadIdx.x; i < nbk; i += blockDim.x) h[i] = 0;
    __syncthreads();
    int i = blockIdx.x * blockDim.x + threadIdx.x;
    int stride = gridDim.x * blockDim.x;
    for (; i < nedges; i += stride) atomicAdd(&h[dst[i] >> BSHIFT], 1);
    __syncthreads();
    for (int i2 = threadIdx.x; i2 < nbk; i2 += blockDim.x)
        if (h[i2]) atomicAdd(&gcount[i2], h[i2]);
}

// single block of 1024 threads; nbk <= 1024. Also writes offsets[n] = E.
__global__ void hgnn_scan(const int* __restrict__ gcount, int* __restrict__ base,
                          int* __restrict__ cursor, int nbk,
                          int* __restrict__ offsets, int n) {
    __shared__ int s[1024];
    int t = threadIdx.x;
    int v = (t < nbk) ? gcount[t] : 0;
    s[t] = v;
    __syncthreads();
    for (int off = 1; off < 1024; off <<= 1) {
        int val = (t >= off) ? s[t - off] : 0;
        __syncthreads();
        s[t] += val;
        __syncthreads();
    }
    if (t < nbk) {
        int excl = s[t] - v;
        base[t] = excl;
        cursor[t] = excl;
    }
    if (t == nbk - 1) {
        base[nbk] = s[t];
        offsets[n] = s[t];   // == E
    }
}

__global__ void hgnn_partition(const int* __restrict__ src,
                               const int* __restrict__ dst,
                               int* __restrict__ cursor,
                               int* __restrict__ part,
                               int nedges, int nbk) {
    __shared__ int h[MAXB];
    __shared__ int lb[MAXB];
    int c0 = blockIdx.x * CE;
    int c1 = min(c0 + CE, nedges);
    for (int i = threadIdx.x; i < nbk; i += blockDim.x) h[i] = 0;
    __syncthreads();
    for (int i = c0 + threadIdx.x; i < c1; i += blockDim.x)
        atomicAdd(&h[dst[i] >> BSHIFT], 1);
    __syncthreads();
    for (int i = threadIdx.x; i < nbk; i += blockDim.x)
        lb[i] = h[i] ? atomicAdd(&cursor[i], h[i]) : 0;
    __syncthreads();
    for (int i = c0 + threadIdx.x; i < c1; i += blockDim.x) {
        int d = dst[i];
        int bk = d >> BSHIFT;
        int pos = atomicAdd(&lb[bk], 1);
        part[pos] = src[i] | ((d & (GNODES - 1)) << 17);
    }
}

// one block per bucket: stage edges in LDS, 128-bin histogram+scan,
// write per-node offsets, scatter back node-sorted (in place).
__global__ void hgnn_refine(int* __restrict__ part, const int* __restrict__ base,
                            int* __restrict__ offsets, int nnodes) {
    __shared__ int ebuf[CAP];
    __shared__ int hist[GNODES];
    __shared__ int cur[GNODES];
    const int b = blockIdx.x;
    const int tid = threadIdx.x;
    const int pbeg = base[b];
    const int cnt = base[b + 1] - pbeg;
    const int nodeBase = b << BSHIFT;

    if (cnt > CAP) {
        // defensive (statistically unreachable): leave bucket unsorted,
        // mark nodes with negative-encoded bucket start.
        for (int r = tid; r < GNODES; r += blockDim.x) {
            int node = nodeBase + r;
            if (node < nnodes) offsets[node] = -(pbeg + 1);
        }
        return;
    }

    for (int i = tid; i < GNODES; i += blockDim.x) hist[i] = 0;
    __syncthreads();
    for (int i = tid; i < cnt; i += blockDim.x) {
        int p = part[pbeg + i];
        ebuf[i] = p;
        atomicAdd(&hist[p >> 17], 1);
    }
    __syncthreads();
    if (tid == 0) {
        int acc = 0;
        for (int i = 0; i < GNODES; ++i) {
            int c = hist[i];
            hist[i] = acc;   // exclusive prefix
            cur[i] = acc;    // running cursor
            acc += c;
        }
    }
    __syncthreads();
    for (int i = tid; i < GNODES; i += blockDim.x) {
        int node = nodeBase + i;
        if (node < nnodes) offsets[node] = pbeg + hist[i];
    }
    for (int i = tid; i < cnt; i += blockDim.x) {
        int p = ebuf[i];
        int pos = atomicAdd(&cur[p >> 17], 1);
        part[pbeg + pos] = p;
    }
}

// one 64-lane wave per node; lane owns one float2 of the 128-d row
__global__ void hgnn_aggregate(const float2* __restrict__ x2,
                               const int* __restrict__ part,
                               const int* __restrict__ offsets,
                               const int* __restrict__ base,
                               float2* __restrict__ out2, int nnodes) {
    int gtid = blockIdx.x * blockDim.x + threadIdx.x;
    int node = gtid >> 6;
    int lane = threadIdx.x & 63;
    if (node >= nnodes) return;

    float2 acc = x2[(long long)node * 64 + lane];   // residual
    int rawb = offsets[node];

    if (rawb >= 0) {
        int rawe = offsets[node + 1];
        int end = (rawe >= 0) ? rawe : (-rawe - 1);
        int j = rawb;
        for (; j + 3 < end; j += 4) {
            int s0 = part[j] & 0x1FFFF;
            int s1 = part[j + 1] & 0x1FFFF;
            int s2 = part[j + 2] & 0x1FFFF;
            int s3 = part[j + 3] & 0x1FFFF;
            float2 v0 = x2[(long long)s0 * 64 + lane];
            float2 v1 = x2[(long long)s1 * 64 + lane];
            float2 v2 = x2[(long long)s2 * 64 + lane];
            float2 v3 = x2[(long long)s3 * 64 + lane];
            acc.x += (v0.x + v1.x) + (v2.x + v3.x);
            acc.y += (v0.y + v1.y) + (v2.y + v3.y);
        }
        for (; j < end; ++j) {
            int s = part[j] & 0x1FFFF;
            float2 v = x2[(long long)s * 64 + lane];
            acc.x += v.x;
            acc.y += v.y;
        }
    } else {
        // unsorted-bucket fallback (never expected on this data)
        int b = node >> BSHIFT;
        int dlocal = node & (GNODES - 1);
        for (int j = base[b]; j < base[b + 1]; ++j) {
            int p = part[j];
            if ((p >> 17) == dlocal) {
                int s = p & 0x1FFFF;
                float2 v = x2[(long long)s * 64 + lane];
                acc.x += v.x;
                acc.y += v.y;
            }
        }
    }
    out2[(long long)node * 64 + lane] = acc;
}

extern "C" void kernel_launch(void* const* d_in, const int* in_sizes, int n_in,
                              void* d_out, int out_size, void* d_ws, size_t ws_size,
                              hipStream_t stream) {
    const float* x = (const float*)d_in[0];
    const int* src = (const int*)d_in[1];
    const int* dst = (const int*)d_in[2];
    float* out = (float*)d_out;

    const int E = in_sizes[1];                   // 2,000,000
    const int N = in_sizes[0] / DIM;             // 100,000
    const int NBK = (N + GNODES - 1) >> BSHIFT;  // 782

    // workspace layout (ints): ~8.5 MB
    int* ws = (int*)d_ws;
    int* gcount  = ws;                    // [MAXB]
    int* base    = gcount + MAXB;         // [MAXB+1]
    int* cursor  = base + MAXB + 1;       // [MAXB]
    int* offsets = cursor + MAXB;         // [N+1]
    int* part    = offsets + (N + 1);     // [E]

    hipMemsetAsync(gcount, 0, (size_t)NBK * sizeof(int), stream);

    hipLaunchKernelGGL(hgnn_hist, dim3(1024), dim3(256), 0, stream,
                       dst, gcount, E, NBK);
    hipLaunchKernelGGL(hgnn_scan, dim3(1), dim3(1024), 0, stream,
                       gcount, base, cursor, NBK, offsets, N);
    hipLaunchKernelGGL(hgnn_partition, dim3((E + CE - 1) / CE), dim3(256), 0, stream,
                       src, dst, cursor, part, E, NBK);
    hipLaunchKernelGGL(hgnn_refine, dim3(NBK), dim3(256), 0, stream,
                       part, base, offsets, N);
    {
        int grid = (N * 64 + 255) / 256;   // one wave per node
        hipLaunchKernelGGL(hgnn_aggregate, dim3(grid), dim3(256), 0, stream,
                           (const float2*)x, part, offsets, base, (float2*)out, N);
    }
}

// Round 6
// 203.978 us; speedup vs baseline: 8.5607x; 1.1416x over previous
//
#include <hip/hip_runtime.h>

// HGNN aggregation: out = x + segment_sum(x[src_idx], dst_idx)
// x: [100000, 128] f32; src_idx/dst_idx: [2,000,000] int32.
//
// Round 6: bf16 gather mirror.
//   1. hist+convert: bucket histogram (dst>>7) + x -> bf16 copy (RTNE)
//   2. single-block scan -> bucket base/cursor
//   3. partition: packed src|(dstLocal<<17), bucket-clustered writes
//   4. refine: per-bucket LDS counting-sort by node, exact offsets
//   5. aggregate: one wave per node, 32 lanes x ushort4 per edge
//      (2 edges per wave-instr, 8 in flight), f32 accum + exact f32
//      residual. Falls back to f32 gather if ws too small.

constexpr int DIM = 128;
constexpr int BSHIFT = 7;            // 128 nodes per bucket
constexpr int GNODES = 1 << BSHIFT;  // 128
constexpr int MAXB = 1024;           // max buckets (N <= 131072)
constexpr int CE = 8192;             // edges per partition block
constexpr int CAP = 8192;            // refine LDS staging capacity (32 KB)

__device__ inline unsigned short f2bf(float f) {
    unsigned u = __float_as_uint(f);
    u = (u + 0x7FFFu + ((u >> 16) & 1u)) >> 16;   // RTNE
    return (unsigned short)u;
}
__device__ inline float bf2f(unsigned short h) {
    return __uint_as_float((unsigned)h << 16);
}

__global__ void hgnn_hist_convert(const int* __restrict__ dst,
                                  int* __restrict__ gcount,
                                  int nedges, int nbk,
                                  const float4* __restrict__ x4,
                                  ushort4* __restrict__ xh4, int n4) {
    __shared__ int h[MAXB];
    for (int i = threadIdx.x; i < nbk; i += blockDim.x) h[i] = 0;
    __syncthreads();
    int i = blockIdx.x * blockDim.x + threadIdx.x;
    int stride = gridDim.x * blockDim.x;
    if (xh4) {
        for (int k = i; k < n4; k += stride) {
            float4 v = x4[k];
            ushort4 o;
            o.x = f2bf(v.x); o.y = f2bf(v.y);
            o.z = f2bf(v.z); o.w = f2bf(v.w);
            xh4[k] = o;
        }
    }
    for (int k = i; k < nedges; k += stride) atomicAdd(&h[dst[k] >> BSHIFT], 1);
    __syncthreads();
    for (int k = threadIdx.x; k < nbk; k += blockDim.x)
        if (h[k]) atomicAdd(&gcount[k], h[k]);
}

// single block of 1024 threads; nbk <= 1024. Also writes offsets[n] = E.
__global__ void hgnn_scan(const int* __restrict__ gcount, int* __restrict__ base,
                          int* __restrict__ cursor, int nbk,
                          int* __restrict__ offsets, int n) {
    __shared__ int s[1024];
    int t = threadIdx.x;
    int v = (t < nbk) ? gcount[t] : 0;
    s[t] = v;
    __syncthreads();
    for (int off = 1; off < 1024; off <<= 1) {
        int val = (t >= off) ? s[t - off] : 0;
        __syncthreads();
        s[t] += val;
        __syncthreads();
    }
    if (t < nbk) {
        int excl = s[t] - v;
        base[t] = excl;
        cursor[t] = excl;
    }
    if (t == nbk - 1) {
        base[nbk] = s[t];
        offsets[n] = s[t];   // == E
    }
}

__global__ void hgnn_partition(const int* __restrict__ src,
                               const int* __restrict__ dst,
                               int* __restrict__ cursor,
                               int* __restrict__ part,
                               int nedges, int nbk) {
    __shared__ int h[MAXB];
    __shared__ int lb[MAXB];
    int c0 = blockIdx.x * CE;
    int c1 = min(c0 + CE, nedges);
    for (int i = threadIdx.x; i < nbk; i += blockDim.x) h[i] = 0;
    __syncthreads();
    for (int i = c0 + threadIdx.x; i < c1; i += blockDim.x)
        atomicAdd(&h[dst[i] >> BSHIFT], 1);
    __syncthreads();
    for (int i = threadIdx.x; i < nbk; i += blockDim.x)
        lb[i] = h[i] ? atomicAdd(&cursor[i], h[i]) : 0;
    __syncthreads();
    for (int i = c0 + threadIdx.x; i < c1; i += blockDim.x) {
        int d = dst[i];
        int bk = d >> BSHIFT;
        int pos = atomicAdd(&lb[bk], 1);
        part[pos] = src[i] | ((d & (GNODES - 1)) << 17);
    }
}

// one block per bucket: stage edges in LDS, 128-bin counting sort in place.
__global__ void hgnn_refine(int* __restrict__ part, const int* __restrict__ base,
                            int* __restrict__ offsets, int nnodes) {
    __shared__ int ebuf[CAP];
    __shared__ int hist[GNODES];
    __shared__ int cur[GNODES];
    const int b = blockIdx.x;
    const int tid = threadIdx.x;
    const int pbeg = base[b];
    const int cnt = base[b + 1] - pbeg;
    const int nodeBase = b << BSHIFT;

    if (cnt > CAP) {
        // defensive (statistically unreachable): leave bucket unsorted.
        for (int r = tid; r < GNODES; r += blockDim.x) {
            int node = nodeBase + r;
            if (node < nnodes) offsets[node] = -(pbeg + 1);
        }
        return;
    }

    for (int i = tid; i < GNODES; i += blockDim.x) hist[i] = 0;
    __syncthreads();
    for (int i = tid; i < cnt; i += blockDim.x) {
        int p = part[pbeg + i];
        ebuf[i] = p;
        atomicAdd(&hist[p >> 17], 1);
    }
    __syncthreads();
    if (tid == 0) {
        int acc = 0;
        for (int i = 0; i < GNODES; ++i) {
            int c = hist[i];
            hist[i] = acc;
            cur[i] = acc;
            acc += c;
        }
    }
    __syncthreads();
    for (int i = tid; i < GNODES; i += blockDim.x) {
        int node = nodeBase + i;
        if (node < nnodes) offsets[node] = pbeg + hist[i];
    }
    for (int i = tid; i < cnt; i += blockDim.x) {
        int p = ebuf[i];
        int pos = atomicAdd(&cur[p >> 17], 1);
        part[pbeg + pos] = p;
    }
}

// bf16 gather: one wave per node; 32 lanes own a row (ushort4 each);
// halves h=0/1 process even/odd edges; shfl_xor(32) combines.
__global__ void hgnn_aggregate_bf16(const float4* __restrict__ x4,
                                    const ushort4* __restrict__ xh4,
                                    const int* __restrict__ part,
                                    const int* __restrict__ offsets,
                                    const int* __restrict__ base,
                                    float4* __restrict__ out4, int nnodes) {
    int gtid = blockIdx.x * blockDim.x + threadIdx.x;
    int node = gtid >> 6;
    if (node >= nnodes) return;
    int lane = threadIdx.x & 63;
    int h = lane >> 5;
    int c = lane & 31;

    float4 acc = make_float4(0.f, 0.f, 0.f, 0.f);
    int rawb = offsets[node];

    if (rawb >= 0) {
        int rawe = offsets[node + 1];
        int end = (rawe >= 0) ? rawe : (-rawe - 1);
        int cnt = end - rawb;
        const int* pp = part + rawb;
        int j = 0;
        for (; j + 8 <= cnt; j += 8) {
            int p0 = pp[j + h];
            int p1 = pp[j + 2 + h];
            int p2 = pp[j + 4 + h];
            int p3 = pp[j + 6 + h];
            ushort4 v0 = xh4[(size_t)(p0 & 0x1FFFF) * 32 + c];
            ushort4 v1 = xh4[(size_t)(p1 & 0x1FFFF) * 32 + c];
            ushort4 v2 = xh4[(size_t)(p2 & 0x1FFFF) * 32 + c];
            ushort4 v3 = xh4[(size_t)(p3 & 0x1FFFF) * 32 + c];
            acc.x += (bf2f(v0.x) + bf2f(v1.x)) + (bf2f(v2.x) + bf2f(v3.x));
            acc.y += (bf2f(v0.y) + bf2f(v1.y)) + (bf2f(v2.y) + bf2f(v3.y));
            acc.z += (bf2f(v0.z) + bf2f(v1.z)) + (bf2f(v2.z) + bf2f(v3.z));
            acc.w += (bf2f(v0.w) + bf2f(v1.w)) + (bf2f(v2.w) + bf2f(v3.w));
        }
        for (; j < cnt; j += 2) {
            int e = j + h;
            if (e < cnt) {
                int p = pp[e];
                ushort4 v = xh4[(size_t)(p & 0x1FFFF) * 32 + c];
                acc.x += bf2f(v.x);
                acc.y += bf2f(v.y);
                acc.z += bf2f(v.z);
                acc.w += bf2f(v.w);
            }
        }
    } else {
        // unsorted-bucket fallback (never expected): h==0 half only
        int b = node >> BSHIFT;
        int dl = node & (GNODES - 1);
        if (h == 0) {
            for (int j2 = base[b]; j2 < base[b + 1]; ++j2) {
                int p = part[j2];
                if ((p >> 17) == dl) {
                    ushort4 v = xh4[(size_t)(p & 0x1FFFF) * 32 + c];
                    acc.x += bf2f(v.x);
                    acc.y += bf2f(v.y);
                    acc.z += bf2f(v.z);
                    acc.w += bf2f(v.w);
                }
            }
        }
    }

    acc.x += __shfl_xor(acc.x, 32);
    acc.y += __shfl_xor(acc.y, 32);
    acc.z += __shfl_xor(acc.z, 32);
    acc.w += __shfl_xor(acc.w, 32);

    if (h == 0) {
        float4 xv = x4[(size_t)node * 32 + c];
        out4[(size_t)node * 32 + c] =
            make_float4(xv.x + acc.x, xv.y + acc.y, xv.z + acc.z, xv.w + acc.w);
    }
}

// f32 fallback (round-5 aggregate), used only if ws can't hold the bf16 mirror
__global__ void hgnn_aggregate_f32(const float2* __restrict__ x2,
                                   const int* __restrict__ part,
                                   const int* __restrict__ offsets,
                                   const int* __restrict__ base,
                                   float2* __restrict__ out2, int nnodes) {
    int gtid = blockIdx.x * blockDim.x + threadIdx.x;
    int node = gtid >> 6;
    int lane = threadIdx.x & 63;
    if (node >= nnodes) return;

    float2 acc = x2[(long long)node * 64 + lane];
    int rawb = offsets[node];
    if (rawb >= 0) {
        int rawe = offsets[node + 1];
        int end = (rawe >= 0) ? rawe : (-rawe - 1);
        int j = rawb;
        for (; j + 3 < end; j += 4) {
            int s0 = part[j] & 0x1FFFF;
            int s1 = part[j + 1] & 0x1FFFF;
            int s2 = part[j + 2] & 0x1FFFF;
            int s3 = part[j + 3] & 0x1FFFF;
            float2 v0 = x2[(long long)s0 * 64 + lane];
            float2 v1 = x2[(long long)s1 * 64 + lane];
            float2 v2 = x2[(long long)s2 * 64 + lane];
            float2 v3 = x2[(long long)s3 * 64 + lane];
            acc.x += (v0.x + v1.x) + (v2.x + v3.x);
            acc.y += (v0.y + v1.y) + (v2.y + v3.y);
        }
        for (; j < end; ++j) {
            int s = part[j] & 0x1FFFF;
            float2 v = x2[(long long)s * 64 + lane];
            acc.x += v.x;
            acc.y += v.y;
        }
    } else {
        int b = node >> BSHIFT;
        int dl = node & (GNODES - 1);
        for (int j = base[b]; j < base[b + 1]; ++j) {
            int p = part[j];
            if ((p >> 17) == dl) {
                int s = p & 0x1FFFF;
                float2 v = x2[(long long)s * 64 + lane];
                acc.x += v.x;
                acc.y += v.y;
            }
        }
    }
    out2[(long long)node * 64 + lane] = acc;
}

extern "C" void kernel_launch(void* const* d_in, const int* in_sizes, int n_in,
                              void* d_out, int out_size, void* d_ws, size_t ws_size,
                              hipStream_t stream) {
    const float* x = (const float*)d_in[0];
    const int* src = (const int*)d_in[1];
    const int* dst = (const int*)d_in[2];
    float* out = (float*)d_out;

    const int E = in_sizes[1];                   // 2,000,000
    const int N = in_sizes[0] / DIM;             // 100,000
    const int NBK = (N + GNODES - 1) >> BSHIFT;  // 782

    // workspace layout
    int* ws = (int*)d_ws;
    int* gcount  = ws;                    // [MAXB]
    int* base    = gcount + MAXB;         // [MAXB+1]
    int* cursor  = base + MAXB + 1;       // [MAXB]
    int* offsets = cursor + MAXB;         // [N+1]
    int* part    = offsets + (N + 1);     // [E]
    size_t baseBytes = ((size_t)(MAXB + MAXB + 1 + MAXB + N + 1 + E) * 4 + 15) & ~(size_t)15;
    size_t xhBytes = (size_t)N * DIM * 2;        // 25.6 MB bf16 mirror
    bool useBf16 = ws_size >= baseBytes + xhBytes;
    ushort* xh = useBf16 ? (ushort*)((char*)d_ws + baseBytes) : nullptr;

    hipMemsetAsync(gcount, 0, (size_t)NBK * sizeof(int), stream);

    hipLaunchKernelGGL(hgnn_hist_convert, dim3(1024), dim3(256), 0, stream,
                       dst, gcount, E, NBK,
                       (const float4*)x, (ushort4*)xh, N * DIM / 4);
    hipLaunchKernelGGL(hgnn_scan, dim3(1), dim3(1024), 0, stream,
                       gcount, base, cursor, NBK, offsets, N);
    hipLaunchKernelGGL(hgnn_partition, dim3((E + CE - 1) / CE), dim3(256), 0, stream,
                       src, dst, cursor, part, E, NBK);
    hipLaunchKernelGGL(hgnn_refine, dim3(NBK), dim3(256), 0, stream,
                       part, base, offsets, N);
    {
        int grid = (N * 64 + 255) / 256;   // one wave per node
        if (useBf16) {
            hipLaunchKernelGGL(hgnn_aggregate_bf16, dim3(grid), dim3(256), 0, stream,
                               (const float4*)x, (const ushort4*)xh, part, offsets,
                               base, (float4*)out, N);
        } else {
            hipLaunchKernelGGL(hgnn_aggregate_f32, dim3(grid), dim3(256), 0, stream,
                               (const float2*)x, part, offsets, base, (float2*)out, N);
        }
    }
}